// Round 12
// baseline (226.405 us; speedup 1.0000x reference)
//
#include <hip/hip_runtime.h>
#include <stdint.h>

// Problem constants (fixed by reference setup_inputs)
#define BB 32
#define NN 131072            // 2^17 points per batch
#define BN (BB * NN)         // 4,194,304 = 2^22
#define TT 32768             // NUM_POINTS_TARGET
#define CELL 0.05f
#define EMPTY64 0xFFFFFFFFFFFFFFFFull
#define LI17 0x1FFFFu

// Output layout in d_out (floats), in return order:
// y_sel [32,32768,3], idx_out [32,32768,2], mask_sel [32,32768],
// ul_idx [BN], ul_idx_inv [BN]
#define Y_OFF   0
#define IDX_OFF (BB * TT * 3)                    // 3,145,728
#define MSK_OFF (IDX_OFF + BB * TT * 2)          // 5,242,880
#define ULI_OFF (MSK_OFF + BB * TT)              // 6,291,456
#define ULV_OFF (ULI_OFF + BN)                   // 10,485,760

#define SCAN_TPB 256
#define SCAN_EPT 16
#define SCAN_EPB (SCAN_TPB * SCAN_EPT)           // 4096
#define SCAN_NBLK (BN / SCAN_EPB)                // 1024

// Bucket-partition pipeline (NO global atomics — rounds 0-4: every global
// atomic is a memory-side RMW at ~25 G ops/s regardless of scope).
// Pairs CHUNK-MAJOR bucket-sorted (round 6: single-writer windows -> full-line
// writebacks). Dedup XCD-batch-affine (round 7: pfirst write amp 6x -> 1x).
// Round 8: HSLOTS 2048 + slot-register pass 2. Rounds 9/10: rank-during-hist,
// shfl scans, group offs2, flag in pfirst bit31; NT only on dense streams
// (NT on scatters defeats L2 line assembly: 8x write amp). Round 11: keygen
// fused into k_part, LDS-staged bucket-sort -> coalesced pairs writeout.
// ROUND 12: pairs split into pk(u32)+pe(u16) (6 B/pt, li=(chunk<<12)|pe);
// top-k partition output moved INTO scanC (ranks/flags/batch stats already in
// registers; scanC remapped XCD-batch-affine so scattered ysel writes line-
// merge in one L2); k_select slimmed to uli gather + ulinv tail.
#define NBK 1024             // hash buckets per batch
#define CHE 4096             // elems per chunk
#define NCH (BN / CHE)       // 1024 chunks total, 32 per batch
#define BPB 8                // buckets per dedup block
#define NGRP (NBK / BPB)     // 128 bucket-groups per batch
#define P4B (BB * NGRP)      // 4096 dedup blocks
#define HSLOTS 2048
#define HMASK (HSLOTS - 1)

typedef float v4f __attribute__((ext_vector_type(4)));
typedef int   v4i __attribute__((ext_vector_type(4)));
typedef unsigned int v4u __attribute__((ext_vector_type(4)));

__device__ __forceinline__ unsigned bucket_of(unsigned key) {
    return (key * 2654435761u) >> 22;            // top 10 bits of mult-hash
}

// Inclusive block scan of one int per thread (256 threads): shfl wave scan +
// one cross-wave combine.
__device__ __forceinline__ int blockscan_incl(int v, int t, int* wsum) {
    int lane = t & 63, wid = t >> 6;
    #pragma unroll
    for (int off = 1; off < 64; off <<= 1) {
        int u = __shfl_up(v, off, 64);
        if (lane >= off) v += u;
    }
    if (lane == 63) wsum[wid] = v;
    __syncthreads();
    int add = 0;
    #pragma unroll
    for (int w = 0; w < 4; w++) if (w < wid) add += wsum[w];
    return v + add;
}

// Fused keygen + hist + offsets + bucket-sort. Per 4096-point chunk:
// quantize x -> key in registers (y reconstructible exactly:
// CELL*(float)g == CELL*rintf(x/CELL)); plain-store keys (L3-resident for
// scanC's conditional read); LDS histogram where the atomicAdd RETURN is the
// within-(chunk,bucket) rank; shfl scan of 1024 buckets; scatter (key, e)
// into LDS stage; barrier; write pk/pe out LINEARLY (coalesced).
__global__ __launch_bounds__(256) void k_part(const float* __restrict__ x,
                                              unsigned int* __restrict__ keys,
                                              unsigned int* __restrict__ pk,
                                              unsigned short* __restrict__ pe,
                                              int* __restrict__ offs2g) {
    __shared__ int h[NBK];
    __shared__ int wsum[4];
    __shared__ unsigned int stgk[CHE];           // 16 KB
    __shared__ unsigned short stge[CHE];         // 8 KB
    int c = blockIdx.x, t = threadIdx.x;
    int b = c >> 5, cb = c & 31;
    int pbase = (b << 17) + (cb << 12);          // flat index of chunk start
    #pragma unroll
    for (int q = 0; q < 4; q++) h[(q << 8) + t] = 0;
    __syncthreads();
    unsigned int key[16];
    unsigned int rnk[16];
    #pragma unroll
    for (int q = 0; q < 4; q++) {                // 4 points per q, 48B x-load
        int e0 = (q << 10) + (t << 2);
        const v4f* xv = (const v4f*)(x + (size_t)(pbase + e0) * 3);
        v4f va = __builtin_nontemporal_load(xv + 0);
        v4f vb = __builtin_nontemporal_load(xv + 1);
        v4f vc = __builtin_nontemporal_load(xv + 2);
        float p[12];
        p[0] = va[0]; p[1] = va[1]; p[2]  = va[2]; p[3]  = va[3];
        p[4] = vb[0]; p[5] = vb[1]; p[6]  = vb[2]; p[7]  = vb[3];
        p[8] = vc[0]; p[9] = vc[1]; p[10] = vc[2]; p[11] = vc[3];
        v4u kv;
        #pragma unroll
        for (int j = 0; j < 4; j++) {
            int g0 = (int)rintf(p[3 * j + 0] / CELL) + 512;
            int g1 = (int)rintf(p[3 * j + 1] / CELL) + 512;
            int g2 = (int)rintf(p[3 * j + 2] / CELL) + 512;
            g0 = min(max(g0, 0), 1023); g1 = min(max(g1, 0), 1023);
            g2 = min(max(g2, 0), 1023);
            kv[j] = ((unsigned int)g0 << 20) | ((unsigned int)g1 << 10)
                  | (unsigned int)g2;
            key[4 * q + j] = kv[j];
        }
        *(v4u*)(keys + pbase + e0) = kv;         // plain: keep in L2/L3
    }
    #pragma unroll
    for (int e = 0; e < 16; e++)
        rnk[e] = atomicAdd(&h[bucket_of(key[e])], 1);    // count AND rank
    __syncthreads();
    // Exclusive scan over 1024 buckets; thread t owns buckets 4t..4t+3.
    v4i hv = *(v4i*)&h[4 * t];
    int cs = hv[0] + hv[1] + hv[2] + hv[3];
    int incl = blockscan_incl(cs, t, wsum);      // includes one barrier
    int p0 = incl - cs;                          // excl prefix of bucket 4t
    int p1 = p0 + hv[0], p2 = p1 + hv[1], p3 = p2 + hv[2];
    int cbase = c << 12;                         // global pair index of chunk start
    if ((t & 1) == 0)                            // bucket 4t is a group boundary
        offs2g[c * NGRP + (t >> 1)] = cbase + p0;
    h[4 * t + 0] = p0; h[4 * t + 1] = p1;        // chunk-local bucket bases
    h[4 * t + 2] = p2; h[4 * t + 3] = p3;
    __syncthreads();
    #pragma unroll
    for (int q = 0; q < 4; q++) {
        #pragma unroll
        for (int j = 0; j < 4; j++) {
            int e = (q << 10) + (t << 2) + j;    // matches load order
            unsigned int ky = key[4 * q + j];
            int r = h[bucket_of(ky)] + (int)rnk[4 * q + j];  // unique in [0,4096)
            stgk[r] = ky;
            stge[r] = (unsigned short)e;
        }
    }
    __syncthreads();
    unsigned int* pkc = pk + ((size_t)c << 12);
    unsigned int* pec = (unsigned int*)(pe + ((size_t)c << 12));  // CHE/2 u32
    #pragma unroll
    for (int k = 0; k < 16; k++) {               // coalesced 4B
        int idx = t + (k << 8);
        pkc[idx] = stgk[idx];
    }
    #pragma unroll
    for (int k = 0; k < 8; k++) {                // coalesced 4B (2 shorts)
        int i2 = t + (k << 8);
        pec[i2] = (unsigned int)stge[2 * i2]
                | ((unsigned int)stge[2 * i2 + 1] << 16);
    }
}

// Dedup: one block per 8-bucket group of one batch, XCD-batch-affine mapping
// (blk = slot*1024 + inner*8 + xcd => all of batch b's blocks on XCD b%8;
// pfirst lines merge in one L2). u64 LDS table, entry=(key<<17)|li: CAS-claim
// carries li; same-key losers do one 64-bit atomicMin. li reconstructed as
// (chunk<<12)|pe. Pass 1 records resolved slots in registers (marr[8],
// statically indexed; total ~1024 << 2048; strided overflow loop for safety).
// Pass 2: one LDS read + store per point. FLAG (first==li) in bit 31.
__global__ __launch_bounds__(256) void k_dedup(
        const unsigned int* __restrict__ pk,
        const unsigned short* __restrict__ pe,
        const int* __restrict__ offs2g,
        int* __restrict__ pfirst) {
    __shared__ unsigned long long ptab[HSLOTS];
    __shared__ int rstart[32];
    __shared__ int rpre[33];
    int g = blockIdx.x, t = threadIdx.x;
    int xcd = g & 7;
    int inner = (g >> 3) & 127;                  // bucket-group 0..127
    int slot = g >> 10;                          // 0..3
    int b = (slot << 3) | xcd;                   // batch; all its blocks on XCD b%8
    #pragma unroll
    for (int q = 0; q < HSLOTS / 256; q++) ptab[(q << 8) + t] = EMPTY64;
    if (t < 32) {
        int c = (b << 5) + t;
        int st = offs2g[c * NGRP + inner];
        int en = (inner == NGRP - 1) ? ((c + 1) << 12) : offs2g[c * NGRP + inner + 1];
        rstart[t] = st;
        rpre[t] = en - st;               // length, prefixed below
    }
    __syncthreads();
    if (t == 0) {
        int run = 0;
        #pragma unroll
        for (int i = 0; i < 32; i++) { int L = rpre[i]; rpre[i] = run; run += L; }
        rpre[32] = run;
    }
    __syncthreads();
    int total = rpre[32];
    unsigned int marr[8];                // statically indexed (rule #20)
    #pragma unroll 8
    for (int k = 0; k < 8; k++) {
        int p = t + (k << 8);
        if (p < total) {
            int lo = 0, hi = 31;         // largest lo with rpre[lo] <= p
            #pragma unroll
            for (int it = 0; it < 5; it++) {
                int mid = (lo + hi + 1) >> 1;
                if (rpre[mid] <= p) lo = mid; else hi = mid - 1;
            }
            int idx = rstart[lo] + (p - rpre[lo]);
            unsigned int ky = pk[idx];
            unsigned int li = ((unsigned int)lo << 12) | pe[idx];
            unsigned long long pr = ((unsigned long long)ky << 17) | li;
            unsigned int s = ((ky * 0x85EBCA6Bu) >> 20) & HMASK;
            for (;;) {
                unsigned long long old = atomicCAS(&ptab[s], EMPTY64, pr);
                if (old == EMPTY64) break;                // claimed (li included)
                if ((unsigned int)(old >> 17) == ky) {    // same voxel
                    if (pr < old) atomicMin(&ptab[s], pr);
                    break;
                }
                s = (s + 1) & HMASK;
            }
            marr[k] = (s << 17) | li;
        }
    }
    for (int p = t + 2048; p < total; p += 256) {   // overflow (ultra-rare)
        int lo = 0, hi = 31;
        #pragma unroll
        for (int it = 0; it < 5; it++) {
            int mid = (lo + hi + 1) >> 1;
            if (rpre[mid] <= p) lo = mid; else hi = mid - 1;
        }
        int idx = rstart[lo] + (p - rpre[lo]);
        unsigned int ky = pk[idx];
        unsigned int li = ((unsigned int)lo << 12) | pe[idx];
        unsigned long long pr = ((unsigned long long)ky << 17) | li;
        unsigned int s = ((ky * 0x85EBCA6Bu) >> 20) & HMASK;
        for (;;) {
            unsigned long long old = atomicCAS(&ptab[s], EMPTY64, pr);
            if (old == EMPTY64) break;
            if ((unsigned int)(old >> 17) == ky) {
                if (pr < old) atomicMin(&ptab[s], pr);
                break;
            }
            s = (s + 1) & HMASK;
        }
    }
    __syncthreads();
    int bbase = b << 17;
    #pragma unroll 8
    for (int k = 0; k < 8; k++) {
        int p = t + (k << 8);
        if (p < total) {
            unsigned int m = marr[k];
            unsigned int li = m & LI17;
            int first = (int)(ptab[m >> 17] & LI17);
            int val = bbase + first;
            if ((unsigned int)first == li) val = (int)((unsigned int)val | 0x80000000u);
            pfirst[bbase + li] = val;
        }
    }
    for (int p = t + 2048; p < total; p += 256) {   // overflow writes
        int lo = 0, hi = 31;
        #pragma unroll
        for (int it = 0; it < 5; it++) {
            int mid = (lo + hi + 1) >> 1;
            if (rpre[mid] <= p) lo = mid; else hi = mid - 1;
        }
        int idx = rstart[lo] + (p - rpre[lo]);
        unsigned int ky = pk[idx];
        unsigned int li = ((unsigned int)lo << 12) | pe[idx];
        unsigned int s = ((ky * 0x85EBCA6Bu) >> 20) & HMASK;
        unsigned long long e;
        while ((unsigned int)((e = ptab[s]) >> 17) != ky) s = (s + 1) & HMASK;
        int first = (int)(e & LI17);
        int val = bbase + first;
        if ((unsigned int)first == li) val = (int)((unsigned int)val | 0x80000000u);
        pfirst[bbase + li] = val;
    }
}

// Streaming flag pass: flag = pfirst sign bit; bitmask + per-block sums.
__global__ void k_scanA2(const int* __restrict__ pfirst,
                         unsigned short* __restrict__ fmask,
                         int* __restrict__ bsums) {
    int blk = blockIdx.x, t = threadIdx.x;
    int base = blk * SCAN_EPB + t * SCAN_EPT;
    const v4i* pv = (const v4i*)(pfirst + base);
    unsigned int bits = 0; int s = 0;
    #pragma unroll
    for (int q = 0; q < 4; q++) {
        v4i p = pv[q];
        #pragma unroll
        for (int e = 0; e < 4; e++) {
            int idx = 4 * q + e;
            int f = (int)((unsigned int)p[e] >> 31);
            bits |= (unsigned int)f << idx;
            s += f;
        }
    }
    fmask[blk * SCAN_TPB + t] = (unsigned short)bits;
    int lane = t & 63, wid = t >> 6;
    __shared__ int wred[4];
    #pragma unroll
    for (int off = 32; off > 0; off >>= 1) s += __shfl_xor(s, off, 64);
    if (lane == 0) wred[wid] = s;
    __syncthreads();
    if (t == 0) bsums[blk] = wred[0] + wred[1] + wred[2] + wred[3];
}

// Scan pass C, now also the top-k partition writer. Every block scans the
// 1024 raw block sums -> its block prefix, its BATCH's flag base/count, and
// grand total U (all from the same LDS scan). Then per-element: exclusive
// rank -> scanArr (int4); ulinv[rank]=pos scatter; stable-partition pos and,
// when pos<TT, ysel/idxout/msel writes (key loaded conditionally per wave).
// Block mapping is XCD-batch-affine (b%8 == blockIdx%8) so the pos-scattered
// output writes of one batch line-merge in a single XCD L2 (round 6 lesson).
__global__ __launch_bounds__(256) void k_scanC(
        const unsigned short* __restrict__ fmask,
        const int* __restrict__ bsums,
        const unsigned int* __restrict__ keys,
        int* __restrict__ scanArr, float* __restrict__ ulinv,
        int* __restrict__ scal,
        float* __restrict__ ysel, float* __restrict__ idxout,
        float* __restrict__ msel) {
    int t = threadIdx.x;
    __shared__ int wsum[4];
    __shared__ int sh2[SCAN_TPB];
    __shared__ int bp;
    // XCD-batch-affine permutation of the 1024 flat scan-blocks.
    int xcd = blockIdx.x & 7, idx2 = blockIdx.x >> 3;
    int b = ((idx2 & 3) << 3) | xcd;             // batch 0..31, b%8 == xcd
    int cb = idx2 >> 2;                          // 0..31
    int f = (b << 5) | cb;                       // flat scan-block id
    int s0 = bsums[4 * t + 0], s1 = bsums[4 * t + 1];
    int s2 = bsums[4 * t + 2], s3 = bsums[4 * t + 3];
    int cs = s0 + s1 + s2 + s3;
    int incl = blockscan_incl(cs, t, wsum);      // 1 barrier inside
    sh2[t] = incl;
    int q = f >> 2, r = f & 3;
    if (t == q) {
        int ex = incl - cs;                      // exclusive prefix of chunk q
        if (r > 0) ex += s0;
        if (r > 1) ex += s1;
        if (r > 2) ex += s2;
        bp = ex;                                 // flags before this scan-block
    }
    if (f == 0 && t == SCAN_TPB - 1) scal[2] = incl;  // total U (for k_select)
    __syncthreads();                             // publish bp + sh2
    int blockpref = bp;
    int U = sh2[SCAN_TPB - 1];
    int bch = b << 3;                            // batch's first chunk (8/batch)
    int batch_base = (bch == 0) ? 0 : sh2[bch - 1];
    int cnt1 = sh2[bch + 7] - batch_base;        // flags in batch b
    unsigned int bits = fmask[f * SCAN_TPB + t];
    int s = __popc(bits);
    int incl2 = blockscan_incl(s, t, wsum);      // 1 barrier inside
    int prefix = blockpref + incl2 - s;          // exclusive rank for elem 0
    int base = f * SCAN_EPB + t * SCAN_EPT;      // flat point index
    int j0 = base - (b << 17);                   // batch-local index of elem 0
    v4i* out = (v4i*)(scanArr + base);
    #pragma unroll
    for (int qq = 0; qq < 4; qq++) {
        v4i o;
        int pos4[4], flag4[4];
        #pragma unroll
        for (int e = 0; e < 4; e++) {
            int idx = 4 * qq + e;
            int fl = (bits >> idx) & 1;
            o[e] = prefix;
            if (fl) ulinv[prefix] = (float)(base + idx);
            int ones_before = prefix - batch_base;
            flag4[e] = fl;
            pos4[e] = fl ? ones_before : cnt1 + (j0 + idx - ones_before);
            prefix += fl;
        }
        out[qq] = o;
        bool want = (pos4[0] < TT) | (pos4[1] < TT) | (pos4[2] < TT) | (pos4[3] < TT);
        if (__any(want)) {
            v4u kv = *(const v4u*)(keys + base + (qq << 2));
            #pragma unroll
            for (int e = 0; e < 4; e++) {
                int pos = pos4[e];
                if (pos < TT) {
                    unsigned int key = kv[e];
                    float y0 = CELL * (float)((int)(key >> 20) - 512);
                    float y1 = CELL * (float)((int)((key >> 10) & 1023) - 512);
                    float y2 = CELL * (float)((int)(key & 1023) - 512);
                    int yo = (b * TT + pos) * 3;
                    ysel[yo + 0] = y0;
                    ysel[yo + 1] = y1;
                    ysel[yo + 2] = y2;
                    int io = (b * TT + pos) * 2;
                    idxout[io + 0] = (float)b;
                    idxout[io + 1] = (float)(j0 + 4 * qq + e);
                    msel[b * TT + pos] = flag4[e] ? 1.0f : 0.0f;
                }
            }
        }
    }
}

// Slim select: uli[i] = scanArr[pfirst[i]&mask] (appearance rank) + ulinv
// sentinel tail. %32 swizzle keeps the gather in the batch's 512 KB window.
__global__ void k_select(const int* __restrict__ pfirst,
                         const int* __restrict__ scanArr,
                         const int* __restrict__ scal,
                         float* __restrict__ uli, float* __restrict__ ulinv) {
    int blk = blockIdx.x;                  // BN/1024 = 4096 blocks
    int b = blk & 31;
    int chunk = blk >> 5;                  // 0..127
    int j0 = (chunk << 10) + (threadIdx.x << 2);
    int i0 = (b << 17) + j0;
    v4i pf = *(const v4i*)(pfirst + i0);
    int U = scal[2];
    v4f ul;
    #pragma unroll
    for (int e = 0; e < 4; e++)
        ul[e] = (float)scanArr[(unsigned int)pf[e] & 0x7FFFFFFFu];
    __builtin_nontemporal_store(ul, (v4f*)(uli + i0));
    #pragma unroll
    for (int e = 0; e < 4; e++) {
        int i = i0 + e;
        if (i >= U) ulinv[i] = (float)BN;  // sentinel tail
    }
}

extern "C" void kernel_launch(void* const* d_in, const int* in_sizes, int n_in,
                              void* d_out, int out_size, void* d_ws, size_t ws_size,
                              hipStream_t stream) {
    const float* x = (const float*)d_in[0];
    float* out = (float*)d_out;
    char* ws = (char*)d_ws;

    // ws layout (bytes): scalars 256 | pfirst BN*4 | scanArr BN*4 | bsums 4096
    //  | fmask BN/16*2 | keys BN*4 | offs2g 512KB | pk BN*4 | pe BN*2 => ~75MB
    int* scal    = (int*)ws;
    int* pfirst  = (int*)(ws + 256);
    int* scanArr = pfirst + BN;
    int* bsums   = scanArr + BN;
    unsigned short* fmask = (unsigned short*)(bsums + 1024);
    unsigned int* keys = (unsigned int*)((char*)fmask + (BN / 16) * 2);
    int* offs2g = (int*)(keys + BN);
    unsigned int* pk = (unsigned int*)(offs2g + NCH * NGRP);
    unsigned short* pe = (unsigned short*)(pk + BN);

    k_part<<<NCH, 256, 0, stream>>>(x, keys, pk, pe, offs2g);
    k_dedup<<<P4B, 256, 0, stream>>>(pk, pe, offs2g, pfirst);
    k_scanA2<<<SCAN_NBLK, SCAN_TPB, 0, stream>>>(pfirst, fmask, bsums);
    k_scanC<<<SCAN_NBLK, SCAN_TPB, 0, stream>>>(fmask, bsums, keys,
                                                scanArr, out + ULV_OFF, scal,
                                                out + Y_OFF, out + IDX_OFF,
                                                out + MSK_OFF);
    k_select<<<BN / 1024, 256, 0, stream>>>(pfirst, scanArr, scal,
                                            out + ULI_OFF, out + ULV_OFF);
}

// Round 13
// 176.770 us; speedup vs baseline: 1.2808x; 1.2808x over previous
//
#include <hip/hip_runtime.h>
#include <stdint.h>

// Problem constants (fixed by reference setup_inputs)
#define BB 32
#define NN 131072            // 2^17 points per batch
#define BN (BB * NN)         // 4,194,304 = 2^22
#define TT 32768             // NUM_POINTS_TARGET
#define CELL 0.05f
#define EMPTY64 0xFFFFFFFFFFFFFFFFull
#define LI17 0x1FFFFu

// Output layout in d_out (floats), in return order:
// y_sel [32,32768,3], idx_out [32,32768,2], mask_sel [32,32768],
// ul_idx [BN], ul_idx_inv [BN]
#define Y_OFF   0
#define IDX_OFF (BB * TT * 3)                    // 3,145,728
#define MSK_OFF (IDX_OFF + BB * TT * 2)          // 5,242,880
#define ULI_OFF (MSK_OFF + BB * TT)              // 6,291,456
#define ULV_OFF (ULI_OFF + BN)                   // 10,485,760

#define SCAN_TPB 256
#define SCAN_EPT 16
#define SCAN_EPB (SCAN_TPB * SCAN_EPT)           // 4096
#define SCAN_NBLK (BN / SCAN_EPB)                // 1024

// Bucket-partition pipeline (NO global atomics — rounds 0-4: every global
// atomic is a memory-side RMW at ~25 G ops/s regardless of scope).
// Pairs CHUNK-MAJOR bucket-sorted (round 6: single-writer windows -> full-line
// writebacks). Dedup XCD-batch-affine (round 7: pfirst write amp 6x -> 1x).
// Round 8: HSLOTS 2048 + slot-register pass 2. Rounds 9/10: rank-during-hist,
// shfl scans, group offs2, flag in pfirst bit31; NT only on dense streams.
// Round 11: keygen fused into k_part, LDS-staged bucket-sort. Round 12:
// pk(u32)+pe(u16) split (kept). ROUND 13: scanC's ulinv scatter (3.5M
// divergent 4B stores) was ~1 line/store = ~224 MB writeback (measured round
// 12; hidden under the poison fill since round 2) — now staged in LDS by
// block-local rank and written as a dense coalesced stream. Partition output
// back in k_select (round 12's scanC-fusion regressed).
#define NBK 1024             // hash buckets per batch
#define CHE 4096             // elems per chunk
#define NCH (BN / CHE)       // 1024 chunks total, 32 per batch
#define BPB 8                // buckets per dedup block
#define NGRP (NBK / BPB)     // 128 bucket-groups per batch
#define P4B (BB * NGRP)      // 4096 dedup blocks
#define HSLOTS 2048
#define HMASK (HSLOTS - 1)

typedef float v4f __attribute__((ext_vector_type(4)));
typedef int   v4i __attribute__((ext_vector_type(4)));
typedef unsigned int v4u __attribute__((ext_vector_type(4)));

__device__ __forceinline__ unsigned bucket_of(unsigned key) {
    return (key * 2654435761u) >> 22;            // top 10 bits of mult-hash
}

// Inclusive block scan of one int per thread (256 threads): shfl wave scan +
// one cross-wave combine.
__device__ __forceinline__ int blockscan_incl(int v, int t, int* wsum) {
    int lane = t & 63, wid = t >> 6;
    #pragma unroll
    for (int off = 1; off < 64; off <<= 1) {
        int u = __shfl_up(v, off, 64);
        if (lane >= off) v += u;
    }
    if (lane == 63) wsum[wid] = v;
    __syncthreads();
    int add = 0;
    #pragma unroll
    for (int w = 0; w < 4; w++) if (w < wid) add += wsum[w];
    return v + add;
}

// Fused keygen + hist + offsets + bucket-sort. Per 4096-point chunk:
// quantize x -> key in registers (y reconstructible exactly:
// CELL*(float)g == CELL*rintf(x/CELL)); plain-store keys; LDS histogram
// where the atomicAdd RETURN is the within-(chunk,bucket) rank; shfl scan of
// 1024 buckets; scatter (key, e) into LDS stage; barrier; write pk/pe out
// LINEARLY (coalesced). offs2g at group granularity.
__global__ __launch_bounds__(256) void k_part(const float* __restrict__ x,
                                              unsigned int* __restrict__ keys,
                                              unsigned int* __restrict__ pk,
                                              unsigned short* __restrict__ pe,
                                              int* __restrict__ offs2g) {
    __shared__ int h[NBK];
    __shared__ int wsum[4];
    __shared__ unsigned int stgk[CHE];           // 16 KB
    __shared__ unsigned short stge[CHE];         // 8 KB
    int c = blockIdx.x, t = threadIdx.x;
    int b = c >> 5, cb = c & 31;
    int pbase = (b << 17) + (cb << 12);          // flat index of chunk start
    #pragma unroll
    for (int q = 0; q < 4; q++) h[(q << 8) + t] = 0;
    __syncthreads();
    unsigned int key[16];
    unsigned int rnk[16];
    #pragma unroll
    for (int q = 0; q < 4; q++) {                // 4 points per q, 48B x-load
        int e0 = (q << 10) + (t << 2);
        const v4f* xv = (const v4f*)(x + (size_t)(pbase + e0) * 3);
        v4f va = __builtin_nontemporal_load(xv + 0);
        v4f vb = __builtin_nontemporal_load(xv + 1);
        v4f vc = __builtin_nontemporal_load(xv + 2);
        float p[12];
        p[0] = va[0]; p[1] = va[1]; p[2]  = va[2]; p[3]  = va[3];
        p[4] = vb[0]; p[5] = vb[1]; p[6]  = vb[2]; p[7]  = vb[3];
        p[8] = vc[0]; p[9] = vc[1]; p[10] = vc[2]; p[11] = vc[3];
        v4u kv;
        #pragma unroll
        for (int j = 0; j < 4; j++) {
            int g0 = (int)rintf(p[3 * j + 0] / CELL) + 512;
            int g1 = (int)rintf(p[3 * j + 1] / CELL) + 512;
            int g2 = (int)rintf(p[3 * j + 2] / CELL) + 512;
            g0 = min(max(g0, 0), 1023); g1 = min(max(g1, 0), 1023);
            g2 = min(max(g2, 0), 1023);
            kv[j] = ((unsigned int)g0 << 20) | ((unsigned int)g1 << 10)
                  | (unsigned int)g2;
            key[4 * q + j] = kv[j];
        }
        *(v4u*)(keys + pbase + e0) = kv;         // plain: keep in L2/L3
    }
    #pragma unroll
    for (int e = 0; e < 16; e++)
        rnk[e] = atomicAdd(&h[bucket_of(key[e])], 1);    // count AND rank
    __syncthreads();
    // Exclusive scan over 1024 buckets; thread t owns buckets 4t..4t+3.
    v4i hv = *(v4i*)&h[4 * t];
    int cs = hv[0] + hv[1] + hv[2] + hv[3];
    int incl = blockscan_incl(cs, t, wsum);      // includes one barrier
    int p0 = incl - cs;                          // excl prefix of bucket 4t
    int p1 = p0 + hv[0], p2 = p1 + hv[1], p3 = p2 + hv[2];
    int cbase = c << 12;                         // global pair index of chunk start
    if ((t & 1) == 0)                            // bucket 4t is a group boundary
        offs2g[c * NGRP + (t >> 1)] = cbase + p0;
    h[4 * t + 0] = p0; h[4 * t + 1] = p1;        // chunk-local bucket bases
    h[4 * t + 2] = p2; h[4 * t + 3] = p3;
    __syncthreads();
    #pragma unroll
    for (int q = 0; q < 4; q++) {
        #pragma unroll
        for (int j = 0; j < 4; j++) {
            int e = (q << 10) + (t << 2) + j;    // matches load order
            unsigned int ky = key[4 * q + j];
            int r = h[bucket_of(ky)] + (int)rnk[4 * q + j];  // unique in [0,4096)
            stgk[r] = ky;
            stge[r] = (unsigned short)e;
        }
    }
    __syncthreads();
    unsigned int* pkc = pk + ((size_t)c << 12);
    unsigned int* pec = (unsigned int*)(pe + ((size_t)c << 12));  // CHE/2 u32
    #pragma unroll
    for (int k = 0; k < 16; k++) {               // coalesced 4B
        int idx = t + (k << 8);
        pkc[idx] = stgk[idx];
    }
    #pragma unroll
    for (int k = 0; k < 8; k++) {                // coalesced 4B (2 shorts)
        int i2 = t + (k << 8);
        pec[i2] = (unsigned int)stge[2 * i2]
                | ((unsigned int)stge[2 * i2 + 1] << 16);
    }
}

// Dedup: one block per 8-bucket group of one batch, XCD-batch-affine mapping
// (blk = slot*1024 + inner*8 + xcd => all of batch b's blocks on XCD b%8;
// pfirst lines merge in one L2). u64 LDS table, entry=(key<<17)|li: CAS-claim
// carries li; same-key losers do one 64-bit atomicMin. li reconstructed as
// (chunk<<12)|pe. Pass 1 records resolved slots in registers (marr[8]);
// pass 2: one LDS read + store per point. FLAG (first==li) in bit 31.
__global__ __launch_bounds__(256) void k_dedup(
        const unsigned int* __restrict__ pk,
        const unsigned short* __restrict__ pe,
        const int* __restrict__ offs2g,
        int* __restrict__ pfirst) {
    __shared__ unsigned long long ptab[HSLOTS];
    __shared__ int rstart[32];
    __shared__ int rpre[33];
    int g = blockIdx.x, t = threadIdx.x;
    int xcd = g & 7;
    int inner = (g >> 3) & 127;                  // bucket-group 0..127
    int slot = g >> 10;                          // 0..3
    int b = (slot << 3) | xcd;                   // batch; all its blocks on XCD b%8
    #pragma unroll
    for (int q = 0; q < HSLOTS / 256; q++) ptab[(q << 8) + t] = EMPTY64;
    if (t < 32) {
        int c = (b << 5) + t;
        int st = offs2g[c * NGRP + inner];
        int en = (inner == NGRP - 1) ? ((c + 1) << 12) : offs2g[c * NGRP + inner + 1];
        rstart[t] = st;
        rpre[t] = en - st;               // length, prefixed below
    }
    __syncthreads();
    if (t == 0) {
        int run = 0;
        #pragma unroll
        for (int i = 0; i < 32; i++) { int L = rpre[i]; rpre[i] = run; run += L; }
        rpre[32] = run;
    }
    __syncthreads();
    int total = rpre[32];
    unsigned int marr[8];                // statically indexed (rule #20)
    #pragma unroll 8
    for (int k = 0; k < 8; k++) {
        int p = t + (k << 8);
        if (p < total) {
            int lo = 0, hi = 31;         // largest lo with rpre[lo] <= p
            #pragma unroll
            for (int it = 0; it < 5; it++) {
                int mid = (lo + hi + 1) >> 1;
                if (rpre[mid] <= p) lo = mid; else hi = mid - 1;
            }
            int idx = rstart[lo] + (p - rpre[lo]);
            unsigned int ky = pk[idx];
            unsigned int li = ((unsigned int)lo << 12) | pe[idx];
            unsigned long long pr = ((unsigned long long)ky << 17) | li;
            unsigned int s = ((ky * 0x85EBCA6Bu) >> 20) & HMASK;
            for (;;) {
                unsigned long long old = atomicCAS(&ptab[s], EMPTY64, pr);
                if (old == EMPTY64) break;                // claimed (li included)
                if ((unsigned int)(old >> 17) == ky) {    // same voxel
                    if (pr < old) atomicMin(&ptab[s], pr);
                    break;
                }
                s = (s + 1) & HMASK;
            }
            marr[k] = (s << 17) | li;
        }
    }
    for (int p = t + 2048; p < total; p += 256) {   // overflow (ultra-rare)
        int lo = 0, hi = 31;
        #pragma unroll
        for (int it = 0; it < 5; it++) {
            int mid = (lo + hi + 1) >> 1;
            if (rpre[mid] <= p) lo = mid; else hi = mid - 1;
        }
        int idx = rstart[lo] + (p - rpre[lo]);
        unsigned int ky = pk[idx];
        unsigned int li = ((unsigned int)lo << 12) | pe[idx];
        unsigned long long pr = ((unsigned long long)ky << 17) | li;
        unsigned int s = ((ky * 0x85EBCA6Bu) >> 20) & HMASK;
        for (;;) {
            unsigned long long old = atomicCAS(&ptab[s], EMPTY64, pr);
            if (old == EMPTY64) break;
            if ((unsigned int)(old >> 17) == ky) {
                if (pr < old) atomicMin(&ptab[s], pr);
                break;
            }
            s = (s + 1) & HMASK;
        }
    }
    __syncthreads();
    int bbase = b << 17;
    #pragma unroll 8
    for (int k = 0; k < 8; k++) {
        int p = t + (k << 8);
        if (p < total) {
            unsigned int m = marr[k];
            unsigned int li = m & LI17;
            int first = (int)(ptab[m >> 17] & LI17);
            int val = bbase + first;
            if ((unsigned int)first == li) val = (int)((unsigned int)val | 0x80000000u);
            pfirst[bbase + li] = val;
        }
    }
    for (int p = t + 2048; p < total; p += 256) {   // overflow writes
        int lo = 0, hi = 31;
        #pragma unroll
        for (int it = 0; it < 5; it++) {
            int mid = (lo + hi + 1) >> 1;
            if (rpre[mid] <= p) lo = mid; else hi = mid - 1;
        }
        int idx = rstart[lo] + (p - rpre[lo]);
        unsigned int ky = pk[idx];
        unsigned int li = ((unsigned int)lo << 12) | pe[idx];
        unsigned int s = ((ky * 0x85EBCA6Bu) >> 20) & HMASK;
        unsigned long long e;
        while ((unsigned int)((e = ptab[s]) >> 17) != ky) s = (s + 1) & HMASK;
        int first = (int)(e & LI17);
        int val = bbase + first;
        if ((unsigned int)first == li) val = (int)((unsigned int)val | 0x80000000u);
        pfirst[bbase + li] = val;
    }
}

// Streaming flag pass: flag = pfirst sign bit; bitmask + per-block sums.
__global__ void k_scanA2(const int* __restrict__ pfirst,
                         unsigned short* __restrict__ fmask,
                         int* __restrict__ bsums) {
    int blk = blockIdx.x, t = threadIdx.x;
    int base = blk * SCAN_EPB + t * SCAN_EPT;
    const v4i* pv = (const v4i*)(pfirst + base);
    unsigned int bits = 0; int s = 0;
    #pragma unroll
    for (int q = 0; q < 4; q++) {
        v4i p = pv[q];
        #pragma unroll
        for (int e = 0; e < 4; e++) {
            int idx = 4 * q + e;
            int f = (int)((unsigned int)p[e] >> 31);
            bits |= (unsigned int)f << idx;
            s += f;
        }
    }
    fmask[blk * SCAN_TPB + t] = (unsigned short)bits;
    int lane = t & 63, wid = t >> 6;
    __shared__ int wred[4];
    #pragma unroll
    for (int off = 32; off > 0; off >>= 1) s += __shfl_xor(s, off, 64);
    if (lane == 0) wred[wid] = s;
    __syncthreads();
    if (t == 0) bsums[blk] = wred[0] + wred[1] + wred[2] + wred[3];
}

// Scan pass C with fused pass B. ROUND 13: the ulinv[rank]=pos scatter is
// staged in LDS by block-local rank (ranks of one block are the contiguous
// range [blockpref, blockpref+cnt)) and written out as a DENSE coalesced
// stream — the divergent per-lane scatter was ~1 full line per 4B store
// (~224 MB writeback, measured round 12).
__global__ __launch_bounds__(256) void k_scanC(
        const unsigned short* __restrict__ fmask,
        const int* __restrict__ bsums,
        int* __restrict__ scanArr, float* __restrict__ ulinv,
        int* __restrict__ scal) {
    int t = threadIdx.x;
    __shared__ int wsum[4];
    __shared__ int bp;
    __shared__ int cnt_sh;
    __shared__ float ustg[SCAN_EPB];             // 16 KB rank-ordered staging
    int s0 = bsums[4 * t + 0], s1 = bsums[4 * t + 1];
    int s2 = bsums[4 * t + 2], s3 = bsums[4 * t + 3];
    int cs = s0 + s1 + s2 + s3;
    int incl = blockscan_incl(cs, t, wsum);      // 1 barrier inside
    int q = blockIdx.x >> 2, r = blockIdx.x & 3;
    if (t == q) {
        int ex = incl - cs;                      // exclusive prefix of chunk q
        if (r > 0) ex += s0;
        if (r > 1) ex += s1;
        if (r > 2) ex += s2;
        bp = ex;                                 // flags before this block
    }
    if (blockIdx.x == 0 && t == SCAN_TPB - 1) scal[2] = incl;  // total U
    __syncthreads();                             // publish bp
    int blockpref = bp;
    unsigned int bits = fmask[blockIdx.x * SCAN_TPB + t];
    int s = __popc(bits);
    int incl2 = blockscan_incl(s, t, wsum);      // 1 barrier inside
    if (t == SCAN_TPB - 1) cnt_sh = incl2;       // block's flag count
    int prefix = blockpref + incl2 - s;          // exclusive rank for elem 0
    int loc = prefix - blockpref;                // block-local rank
    int base = blockIdx.x * SCAN_EPB + t * SCAN_EPT;
    v4i* out = (v4i*)(scanArr + base);
    #pragma unroll
    for (int qq = 0; qq < 4; qq++) {
        v4i o;
        #pragma unroll
        for (int e = 0; e < 4; e++) {
            int idx = 4 * qq + e;
            int f = (bits >> idx) & 1;
            o[e] = prefix;
            if (f) ustg[loc] = (float)(base + idx);
            loc += f;
            prefix += f;
        }
        out[qq] = o;
    }
    __syncthreads();                             // ustg + cnt_sh ready
    int cnt = cnt_sh;
    float* up = ulinv + blockpref;
    for (int i = t; i < cnt; i += 256) up[i] = ustg[i];   // dense coalesced
}

// Fused: ul_idx gather + ul_idx_inv tail pad + stable top-k partition +
// output gather. Flag from pfirst bit31; keys loaded only in waves where some
// lane writes (pos<TT). %32 swizzle keeps gathers/writes batch-local.
__global__ void k_select(const unsigned int* __restrict__ keys,
                         const int* __restrict__ pfirst,
                         const int* __restrict__ scanArr,
                         const int* __restrict__ scal,
                         float* __restrict__ ysel, float* __restrict__ idxout,
                         float* __restrict__ msel, float* __restrict__ uli,
                         float* __restrict__ ulinv) {
    int blk = blockIdx.x;                  // BN/1024 = 4096 blocks
    int b = blk & 31;
    int chunk = blk >> 5;                  // 0..127
    int j0 = (chunk << 10) + (threadIdx.x << 2);
    int i0 = (b << 17) + j0;
    v4i pf = *(const v4i*)(pfirst + i0);
    v4i sa = *(const v4i*)(scanArr + i0);
    int U = scal[2];
    int base = scanArr[b << 17];
    int cnt1 = ((b == BB - 1) ? U : scanArr[(b + 1) << 17]) - base;
    v4f ul;
    int pos4[4], flag4[4];
    #pragma unroll
    for (int e = 0; e < 4; e++) {
        unsigned int pv = (unsigned int)pf[e];
        ul[e] = (float)scanArr[pv & 0x7FFFFFFFu];
        int flag = (int)(pv >> 31);
        int ones_before = sa[e] - base;
        int j = j0 + e;
        flag4[e] = flag;
        pos4[e] = flag ? ones_before : cnt1 + (j - ones_before);
    }
    __builtin_nontemporal_store(ul, (v4f*)(uli + i0));
    bool want = (pos4[0] < TT) | (pos4[1] < TT) | (pos4[2] < TT) | (pos4[3] < TT);
    if (__any(want)) {
        v4u kv = *(const v4u*)(keys + i0);
        #pragma unroll
        for (int e = 0; e < 4; e++) {
            int pos = pos4[e];
            if (pos < TT) {
                unsigned int key = kv[e];
                float y0 = CELL * (float)((int)(key >> 20) - 512);
                float y1 = CELL * (float)((int)((key >> 10) & 1023) - 512);
                float y2 = CELL * (float)((int)(key & 1023) - 512);
                int yo = (b * TT + pos) * 3;
                ysel[yo + 0] = y0;
                ysel[yo + 1] = y1;
                ysel[yo + 2] = y2;
                int io = (b * TT + pos) * 2;
                idxout[io + 0] = (float)b;
                idxout[io + 1] = (float)(j0 + e);
                msel[b * TT + pos] = flag4[e] ? 1.0f : 0.0f;
            }
        }
    }
    #pragma unroll
    for (int e = 0; e < 4; e++) {
        int i = i0 + e;
        if (i >= U) ulinv[i] = (float)BN;  // sentinel tail
    }
}

extern "C" void kernel_launch(void* const* d_in, const int* in_sizes, int n_in,
                              void* d_out, int out_size, void* d_ws, size_t ws_size,
                              hipStream_t stream) {
    const float* x = (const float*)d_in[0];
    float* out = (float*)d_out;
    char* ws = (char*)d_ws;

    // ws layout (bytes): scalars 256 | pfirst BN*4 | scanArr BN*4 | bsums 4096
    //  | fmask BN/16*2 | keys BN*4 | offs2g 512KB | pk BN*4 | pe BN*2 => ~75MB
    int* scal    = (int*)ws;
    int* pfirst  = (int*)(ws + 256);
    int* scanArr = pfirst + BN;
    int* bsums   = scanArr + BN;
    unsigned short* fmask = (unsigned short*)(bsums + 1024);
    unsigned int* keys = (unsigned int*)((char*)fmask + (BN / 16) * 2);
    int* offs2g = (int*)(keys + BN);
    unsigned int* pk = (unsigned int*)(offs2g + NCH * NGRP);
    unsigned short* pe = (unsigned short*)(pk + BN);

    k_part<<<NCH, 256, 0, stream>>>(x, keys, pk, pe, offs2g);
    k_dedup<<<P4B, 256, 0, stream>>>(pk, pe, offs2g, pfirst);
    k_scanA2<<<SCAN_NBLK, SCAN_TPB, 0, stream>>>(pfirst, fmask, bsums);
    k_scanC<<<SCAN_NBLK, SCAN_TPB, 0, stream>>>(fmask, bsums, scanArr, out + ULV_OFF,
                                                scal);
    k_select<<<BN / 1024, 256, 0, stream>>>(keys, pfirst, scanArr, scal,
                                            out + Y_OFF, out + IDX_OFF, out + MSK_OFF,
                                            out + ULI_OFF, out + ULV_OFF);
}